// Round 5
// baseline (254.708 us; speedup 1.0000x reference)
//
#include <hip/hip_runtime.h>
#include <math.h>

#define NSLICE 64
#define DVEC   131072          // float4 per slice (524288 floats / 4)
#define NB     32              // chunks per slice
#define CHUNK4 (DVEC / NB)     // 4096 float4 per chunk (64 KiB)
#define TPB    256
#define ITER   (CHUNK4 / TPB)  // 16 float4 per thread per stream
#define NPAIR  (NSLICE - 1)    // 63 adjacent pairs
#define NTASKA (NPAIR * NB)    // 2016 cross tasks
#define NTASK  (NSLICE * NB)   // 2048 per-slice tasks

typedef float f32x4 __attribute__((ext_vector_type(4)));

__inline__ __device__ void nt_store4(const float4& v, float4* p) {
    __builtin_nontemporal_store(*reinterpret_cast<const f32x4*>(&v),
                                reinterpret_cast<f32x4*>(p));
}

__inline__ __device__ float wave_reduce(float v) {
    #pragma unroll
    for (int off = 32; off > 0; off >>= 1) v += __shfl_down(v, off, 64);
    return v;
}

// local-max test (case c1: the only case whose softmax doesn't saturate).
__inline__ __device__ bool is_c1(const float* __restrict__ ent, int s) {
    if (s < 1 || s > NSLICE - 2) return false;
    const float e = ent[s];
    return (e >= ent[s + 1]) && (e >= ent[s - 1]);
}

// copy-source for saturated slices; reports whether slice i blends instead.
__inline__ __device__ int copy_src(const float* __restrict__ ent, int i, bool* blend) {
    *blend = false;
    if (i == 0)          return (ent[0] >= ent[1]) ? 1 : 0;              // (.5,.5) same slice
    if (i == NSLICE - 1) return (ent[NSLICE-1] >= ent[NSLICE-2]) ? NSLICE-2 : NSLICE-1;
    const float ei = ent[i], ep = ent[i-1], en = ent[i+1];
    if ((ei >= en) && (ei >= ep)) { *blend = true; return i; }           // c1: genuine blend
    // c2:(0,1)->q[i]; c3:(1,0)->q[i]; c4:(.5,.5)->q[i]
    return i;
}

// Kernel 1: pure streaming copy for saturated slices (out[i] = q[src]).
// No LDS, no syncs, one read stream + one nt-write stream per block.
// Warms L3 with every non-peak slice (all cross-dot neighbor operands).
__global__ __launch_bounds__(TPB) void copy_kernel(
        const float4* __restrict__ q, const float* __restrict__ ent,
        float4* __restrict__ out) {
    const int task = blockIdx.x;
    const int i = task >> 5;
    const int j = task & 31;
    const int tid = threadIdx.x;

    bool blend;
    const int src = copy_src(ent, i, &blend);
    if (blend) return;                         // block-uniform early exit

    const float4* qs = q + (size_t)src * DVEC + (size_t)j * CHUNK4 + tid;
    float4* o = out + (size_t)i * DVEC + (size_t)j * CHUNK4 + tid;
    #pragma unroll
    for (int t = 0; t < ITER; t += 8) {
        float4 x0 = qs[(t+0)*TPB]; float4 x1 = qs[(t+1)*TPB];
        float4 x2 = qs[(t+2)*TPB]; float4 x3 = qs[(t+3)*TPB];
        float4 x4 = qs[(t+4)*TPB]; float4 x5 = qs[(t+5)*TPB];
        float4 x6 = qs[(t+6)*TPB]; float4 x7 = qs[(t+7)*TPB];
        nt_store4(x0, &o[(t+0)*TPB]); nt_store4(x1, &o[(t+1)*TPB]);
        nt_store4(x2, &o[(t+2)*TPB]); nt_store4(x3, &o[(t+3)*TPB]);
        nt_store4(x4, &o[(t+4)*TPB]); nt_store4(x5, &o[(t+5)*TPB]);
        nt_store4(x6, &o[(t+6)*TPB]); nt_store4(x7, &o[(t+7)*TPB]);
    }
}

// Kernel 2: gated partial cross-dot pC[pair,chunk] = dot-part(q[i], q[i+1]),
// only for pairs a local-max slice will consume. Neighbor slices are L3-hot
// from kernel 1; peak slices are the only cold reads.
__global__ __launch_bounds__(TPB) void cross_kernel(
        const float4* __restrict__ q, const float* __restrict__ ent,
        float* __restrict__ pC) {
    const int task = blockIdx.x;
    const int i = task >> 5;       // pair index 0..62
    const int j = task & 31;

    if (!(is_c1(ent, i) || is_c1(ent, i + 1))) return;   // block-uniform

    const float4* qi = q + (size_t)i * DVEC + (size_t)j * CHUNK4 + threadIdx.x;
    const float4* qn = qi + DVEC;
    float c0 = 0.f, c1 = 0.f, c2 = 0.f, c3 = 0.f;
    #pragma unroll
    for (int t = 0; t < ITER; t += 4) {
        float4 a0 = qi[(t+0)*TPB]; float4 a1 = qi[(t+1)*TPB];
        float4 a2 = qi[(t+2)*TPB]; float4 a3 = qi[(t+3)*TPB];
        float4 b0 = qn[(t+0)*TPB]; float4 b1 = qn[(t+1)*TPB];
        float4 b2 = qn[(t+2)*TPB]; float4 b3 = qn[(t+3)*TPB];
        c0 += a0.x*b0.x + a0.y*b0.y + a0.z*b0.z + a0.w*b0.w;
        c1 += a1.x*b1.x + a1.y*b1.y + a1.z*b1.z + a1.w*b1.w;
        c2 += a2.x*b2.x + a2.y*b2.y + a2.z*b2.z + a2.w*b2.w;
        c3 += a3.x*b3.x + a3.y*b3.y + a3.z*b3.z + a3.w*b3.w;
    }
    const float cross = (c0 + c1) + (c2 + c3);

    __shared__ float r_c[TPB / 64];
    const float cw = wave_reduce(cross);
    if ((threadIdx.x & 63) == 0) r_c[threadIdx.x >> 6] = cw;
    __syncthreads();
    if (threadIdx.x == 0) pC[task] = r_c[0] + r_c[1] + r_c[2] + r_c[3];
}

// Kernel 3: blend pass for local-max slices only; everything it reads is
// L3-hot (neighbors from kernel 1, partials from kernel 2).
__global__ __launch_bounds__(TPB) void blend_kernel(
        const float4* __restrict__ q, const float* __restrict__ ent,
        const float* __restrict__ pC, float4* __restrict__ out) {
    const int task = blockIdx.x;
    const int i = task >> 5;
    const int j = task & 31;
    const int tid = threadIdx.x;

    if (!is_c1(ent, i)) return;   // block-uniform early exit

    __shared__ float sp[64];
    if (tid < 64)
        sp[tid] = (tid < 32) ? pC[(i - 1) * NB + tid] : pC[i * NB + (tid - 32)];
    __syncthreads();
    float s1a = 0.f, s2a = 0.f;
    #pragma unroll
    for (int t = 0; t < NB; t++) { s1a += sp[t]; s2a += sp[32 + t]; }

    const float s_scale = 1.0f / sqrtf(524288.0f);
    const float s1 = s1a * s_scale, s2 = s2a * s_scale;
    const float m  = fmaxf(s1, s2);
    const float e1 = expf(s1 - m), e2 = expf(s2 - m);
    const float inv = 1.0f / (e1 + e2);
    const float wa = e1 * inv, wb = e2 * inv;

    const float4* qa = q + (size_t)(i - 1) * DVEC + (size_t)j * CHUNK4 + tid;
    const float4* qb = q + (size_t)(i + 1) * DVEC + (size_t)j * CHUNK4 + tid;
    float4* o = out + (size_t)i * DVEC + (size_t)j * CHUNK4 + tid;
    #pragma unroll
    for (int t = 0; t < ITER; t += 4) {
        float4 x0 = qa[(t+0)*TPB]; float4 x1 = qa[(t+1)*TPB];
        float4 x2 = qa[(t+2)*TPB]; float4 x3 = qa[(t+3)*TPB];
        float4 y0 = qb[(t+0)*TPB]; float4 y1 = qb[(t+1)*TPB];
        float4 y2 = qb[(t+2)*TPB]; float4 y3 = qb[(t+3)*TPB];
        float4 r0, r1, r2, r3;
        r0.x = wa*x0.x + wb*y0.x; r0.y = wa*x0.y + wb*y0.y;
        r0.z = wa*x0.z + wb*y0.z; r0.w = wa*x0.w + wb*y0.w;
        r1.x = wa*x1.x + wb*y1.x; r1.y = wa*x1.y + wb*y1.y;
        r1.z = wa*x1.z + wb*y1.z; r1.w = wa*x1.w + wb*y1.w;
        r2.x = wa*x2.x + wb*y2.x; r2.y = wa*x2.y + wb*y2.y;
        r2.z = wa*x2.z + wb*y2.z; r2.w = wa*x2.w + wb*y2.w;
        r3.x = wa*x3.x + wb*y3.x; r3.y = wa*x3.y + wb*y3.y;
        r3.z = wa*x3.z + wb*y3.z; r3.w = wa*x3.w + wb*y3.w;
        nt_store4(r0, &o[(t+0)*TPB]); nt_store4(r1, &o[(t+1)*TPB]);
        nt_store4(r2, &o[(t+2)*TPB]); nt_store4(r3, &o[(t+3)*TPB]);
    }
}

extern "C" void kernel_launch(void* const* d_in, const int* in_sizes, int n_in,
                              void* d_out, int out_size, void* d_ws, size_t ws_size,
                              hipStream_t stream) {
    const float4* c5d = (const float4*)d_in[0];
    const float*  ent = (const float*)d_in[1];
    float4* out = (float4*)d_out;
    float* pC = (float*)d_ws;   // pC[2016]; only needed slots written & read

    copy_kernel <<<NTASK,  TPB, 0, stream>>>(c5d, ent, out);
    cross_kernel<<<NTASKA, TPB, 0, stream>>>(c5d, ent, pC);
    blend_kernel<<<NTASK,  TPB, 0, stream>>>(c5d, ent, pC, out);
}

// Round 6
// 247.359 us; speedup vs baseline: 1.0297x; 1.0297x over previous
//
#include <hip/hip_runtime.h>
#include <math.h>

#define NSLICE 64
#define DVEC   131072          // float4 per slice (524288 floats / 4)
#define NB     32              // chunks per slice
#define CHUNK4 (DVEC / NB)     // 4096 float4 per chunk (64 KiB)
#define TPB    256
#define ITER   (CHUNK4 / TPB)  // 16 float4 per thread per stream
#define NTASK  (NSLICE * NB)   // 2048 per-slice tasks

typedef float f32x4 __attribute__((ext_vector_type(4)));

__inline__ __device__ void nt_store4(const float4& v, float4* p) {
    __builtin_nontemporal_store(*reinterpret_cast<const f32x4*>(&v),
                                reinterpret_cast<f32x4*>(p));
}

__inline__ __device__ float wave_reduce(float v) {
    #pragma unroll
    for (int off = 32; off > 0; off >>= 1) v += __shfl_down(v, off, 64);
    return v;
}

// local-max test (case c1: the only case whose softmax doesn't saturate).
__inline__ __device__ bool is_c1(const float* __restrict__ ent, int s) {
    if (s < 1 || s > NSLICE - 2) return false;
    const float e = ent[s];
    return (e >= ent[s + 1]) && (e >= ent[s - 1]);
}

// Kernel 1: per (peak slice i, chunk j) block reads 3 streams ONCE
// (q[i-1], q[i], q[i+1]) and emits partials of BOTH dots:
//   pA[i,j] = partial dot(q[i-1], q[i]),  pB[i,j] = partial dot(q[i], q[i+1]).
// vs round-2's per-pair version this avoids the double read of q[i]
// (~40 MB less cold HBM) and runs half as many active blocks.
__global__ __launch_bounds__(TPB) void peak_dots_kernel(
        const float4* __restrict__ q, const float* __restrict__ ent,
        float* __restrict__ pA, float* __restrict__ pB) {
    const int task = blockIdx.x;
    const int i = task >> 5;
    const int j = task & 31;
    const int tid = threadIdx.x;

    if (!is_c1(ent, i)) return;   // block-uniform; peaks are interior only

    const float4* qm = q + (size_t)(i - 1) * DVEC + (size_t)j * CHUNK4 + tid;
    const float4* qi = qm + DVEC;
    const float4* qp = qi + DVEC;

    float u0 = 0.f, u1 = 0.f, v0 = 0.f, v1 = 0.f;
    #pragma unroll
    for (int t = 0; t < ITER; t += 2) {
        float4 a0 = qm[(t+0)*TPB]; float4 a1 = qm[(t+1)*TPB];
        float4 b0 = qi[(t+0)*TPB]; float4 b1 = qi[(t+1)*TPB];
        float4 c0 = qp[(t+0)*TPB]; float4 c1 = qp[(t+1)*TPB];
        u0 += a0.x*b0.x + a0.y*b0.y + a0.z*b0.z + a0.w*b0.w;
        u1 += a1.x*b1.x + a1.y*b1.y + a1.z*b1.z + a1.w*b1.w;
        v0 += b0.x*c0.x + b0.y*c0.y + b0.z*c0.z + b0.w*c0.w;
        v1 += b1.x*c1.x + b1.y*c1.y + b1.z*c1.z + b1.w*c1.w;
    }
    const float s1p = u0 + u1;   // partial dot(q[i-1], q[i])
    const float s2p = v0 + v1;   // partial dot(q[i],   q[i+1])

    __shared__ float r_a[TPB / 64];
    __shared__ float r_b[TPB / 64];
    const float aw = wave_reduce(s1p);
    const float bw = wave_reduce(s2p);
    if ((tid & 63) == 0) { r_a[tid >> 6] = aw; r_b[tid >> 6] = bw; }
    __syncthreads();
    if (tid == 0) {
        pA[task] = r_a[0] + r_a[1] + r_a[2] + r_a[3];
        pB[task] = r_b[0] + r_b[1] + r_b[2] + r_b[3];
    }
}

// Kernel 2 (identical to the round-2 best): saturated slices are a bitwise
// copy of one source slice; local-max slices blend q[i-1], q[i+1] with
// softmax weights from the two dots.
__global__ __launch_bounds__(TPB) void combine_kernel(
        const float4* __restrict__ q, const float* __restrict__ ent,
        const float* __restrict__ pA, const float* __restrict__ pB,
        float4* __restrict__ out) {
    const int task = blockIdx.x;
    const int i = task >> 5;
    const int j = task & 31;
    const int tid = threadIdx.x;

    // classify (block-uniform; replicates the reference branch ladder)
    bool blend = false;
    int src = i;
    if (i == 0) {
        src = (ent[0] >= ent[1]) ? 1 : 0;                     // (.5,.5) same slice
    } else if (i == NSLICE - 1) {
        src = (ent[NSLICE-1] >= ent[NSLICE-2]) ? NSLICE-2 : NSLICE-1;
    } else {
        const float ei = ent[i], ep = ent[i-1], en = ent[i+1];
        if ((ei >= en) && (ei >= ep)) blend = true;           // c1
        // c2:(0,1)->q[i]; c3:(1,0)->q[i]; c4:(.5,.5)->q[i]
    }

    float4* o = out + (size_t)i * DVEC + (size_t)j * CHUNK4 + tid;

    if (!blend) {
        const float4* qs = q + (size_t)src * DVEC + (size_t)j * CHUNK4 + tid;
        #pragma unroll
        for (int t = 0; t < ITER; t += 8) {
            float4 x0 = qs[(t+0)*TPB]; float4 x1 = qs[(t+1)*TPB];
            float4 x2 = qs[(t+2)*TPB]; float4 x3 = qs[(t+3)*TPB];
            float4 x4 = qs[(t+4)*TPB]; float4 x5 = qs[(t+5)*TPB];
            float4 x6 = qs[(t+6)*TPB]; float4 x7 = qs[(t+7)*TPB];
            nt_store4(x0, &o[(t+0)*TPB]); nt_store4(x1, &o[(t+1)*TPB]);
            nt_store4(x2, &o[(t+2)*TPB]); nt_store4(x3, &o[(t+3)*TPB]);
            nt_store4(x4, &o[(t+4)*TPB]); nt_store4(x5, &o[(t+5)*TPB]);
            nt_store4(x6, &o[(t+6)*TPB]); nt_store4(x7, &o[(t+7)*TPB]);
        }
        return;
    }

    // blend path: stage the 64 partials for peak i through LDS.
    __shared__ float sp[64];
    if (tid < 64)
        sp[tid] = (tid < 32) ? pA[i * NB + tid] : pB[i * NB + (tid - 32)];
    __syncthreads();
    float s1a = 0.f, s2a = 0.f;
    #pragma unroll
    for (int t = 0; t < NB; t++) { s1a += sp[t]; s2a += sp[32 + t]; }

    const float s_scale = 1.0f / sqrtf(524288.0f);
    const float s1 = s1a * s_scale, s2 = s2a * s_scale;
    const float m  = fmaxf(s1, s2);
    const float e1 = expf(s1 - m), e2 = expf(s2 - m);
    const float inv = 1.0f / (e1 + e2);
    const float wa = e1 * inv, wb = e2 * inv;

    const float4* qa = q + (size_t)(i - 1) * DVEC + (size_t)j * CHUNK4 + tid;
    const float4* qb = q + (size_t)(i + 1) * DVEC + (size_t)j * CHUNK4 + tid;
    #pragma unroll
    for (int t = 0; t < ITER; t += 4) {
        float4 x0 = qa[(t+0)*TPB]; float4 x1 = qa[(t+1)*TPB];
        float4 x2 = qa[(t+2)*TPB]; float4 x3 = qa[(t+3)*TPB];
        float4 y0 = qb[(t+0)*TPB]; float4 y1 = qb[(t+1)*TPB];
        float4 y2 = qb[(t+2)*TPB]; float4 y3 = qb[(t+3)*TPB];
        float4 r0, r1, r2, r3;
        r0.x = wa*x0.x + wb*y0.x; r0.y = wa*x0.y + wb*y0.y;
        r0.z = wa*x0.z + wb*y0.z; r0.w = wa*x0.w + wb*y0.w;
        r1.x = wa*x1.x + wb*y1.x; r1.y = wa*x1.y + wb*y1.y;
        r1.z = wa*x1.z + wb*y1.z; r1.w = wa*x1.w + wb*y1.w;
        r2.x = wa*x2.x + wb*y2.x; r2.y = wa*x2.y + wb*y2.y;
        r2.z = wa*x2.z + wb*y2.z; r2.w = wa*x2.w + wb*y2.w;
        r3.x = wa*x3.x + wb*y3.x; r3.y = wa*x3.y + wb*y3.y;
        r3.z = wa*x3.z + wb*y3.z; r3.w = wa*x3.w + wb*y3.w;
        nt_store4(r0, &o[(t+0)*TPB]); nt_store4(r1, &o[(t+1)*TPB]);
        nt_store4(r2, &o[(t+2)*TPB]); nt_store4(r3, &o[(t+3)*TPB]);
    }
}

extern "C" void kernel_launch(void* const* d_in, const int* in_sizes, int n_in,
                              void* d_out, int out_size, void* d_ws, size_t ws_size,
                              hipStream_t stream) {
    const float4* c5d = (const float4*)d_in[0];
    const float*  ent = (const float*)d_in[1];
    float4* out = (float4*)d_out;

    // workspace: pA[2048] | pB[2048]; only peak slots written & read -> no memset
    float* pA = (float*)d_ws;
    float* pB = pA + NTASK;

    peak_dots_kernel<<<NTASK, TPB, 0, stream>>>(c5d, ent, pA, pB);
    combine_kernel  <<<NTASK, TPB, 0, stream>>>(c5d, ent, pA, pB, out);
}